// Round 6
// baseline (204.603 us; speedup 1.0000x reference)
//
#include <hip/hip_runtime.h>
#include <hip/hip_bf16.h>
#include <math.h>

#define SEQ 4096
#define EDIM 768
#define NHEAD 12
#define HDIM 64
#define SE (SEQ * EDIM)
#define WMAT (EDIM * EDIM)
#define QSCALE 0.180336880111f  // 0.125 * log2(e)

typedef __attribute__((ext_vector_type(8))) __bf16 bf16x8;
typedef __attribute__((ext_vector_type(4))) float f32x4;
typedef __attribute__((ext_vector_type(8))) unsigned short u16x8;
typedef unsigned short ushort_t;
typedef unsigned int uint_t;

#define MFMA16(a, b, c) __builtin_amdgcn_mfma_f32_16x16x32_bf16(a, b, c, 0, 0, 0)
#define GLOAD_LDS16(g, l)                                          \
  __builtin_amdgcn_global_load_lds(                                \
      (const __attribute__((address_space(1))) void*)(g),          \
      (__attribute__((address_space(3))) void*)(l), 16, 0, 0)

__device__ __forceinline__ unsigned short bfbits(float x) {
  return __builtin_bit_cast(unsigned short, (__bf16)x);
}
__device__ __forceinline__ void split1(float x, unsigned short* h,
                                       unsigned short* l) {
  __bf16 hb = (__bf16)x;
  *h = __builtin_bit_cast(unsigned short, hb);
  *l = __builtin_bit_cast(unsigned short, (__bf16)(x - (float)hb));
}
__device__ __forceinline__ bf16x8 ones8() {
  u16x8 u;
#pragma unroll
  for (int e = 0; e < 8; ++e) u[e] = 0x3F80;  // bf16 1.0
  return __builtin_bit_cast(bf16x8, u);
}

// ---------------------------------------------------------------------------
// Prep: round Wq/Wk/Wv to bf16; split Wo hi/lo; round x to bf16.
// ---------------------------------------------------------------------------
__global__ __launch_bounds__(256) void wprep_kernel(
    const float* __restrict__ W0, const float* __restrict__ W1,
    const float* __restrict__ W2, const float* __restrict__ W3,
    ushort_t* __restrict__ WB, ushort_t* __restrict__ WOH,
    ushort_t* __restrict__ WOL) {
  const int m = blockIdx.y;
  const float* src = (m == 0) ? W0 : (m == 1) ? W1 : (m == 2) ? W2 : W3;
  const size_t i = ((size_t)blockIdx.x * 256 + threadIdx.x) * 8;
  float4 a = *(const float4*)(src + i);
  float4 b = *(const float4*)(src + i + 4);
  float fv[8] = {a.x, a.y, a.z, a.w, b.x, b.y, b.z, b.w};
  if (m < 3) {
    u16x8 hh;
#pragma unroll
    for (int e = 0; e < 8; ++e) hh[e] = bfbits(fv[e]);
    *(u16x8*)(WB + (size_t)m * WMAT + i) = hh;
  } else {
    u16x8 hh, ll;
#pragma unroll
    for (int e = 0; e < 8; ++e) {
      unsigned short x, y;
      split1(fv[e], &x, &y);
      hh[e] = x;
      ll[e] = y;
    }
    *(u16x8*)(WOH + i) = hh;
    *(u16x8*)(WOL + i) = ll;
  }
}

__global__ __launch_bounds__(256) void xprep_kernel(
    const float* __restrict__ x, ushort_t* __restrict__ xb) {
  const size_t i = ((size_t)blockIdx.x * 256 + threadIdx.x) * 8;
  float4 a = *(const float4*)(x + i);
  float4 b = *(const float4*)(x + i + 4);
  float fv[8] = {a.x, a.y, a.z, a.w, b.x, b.y, b.z, b.w};
  u16x8 hh;
#pragma unroll
  for (int e = 0; e < 8; ++e) hh[e] = bfbits(fv[e]);
  *(u16x8*)(xb + i) = hh;
}

// ---------------------------------------------------------------------------
// Single-bf16 MFMA GEMM (for QKV): out_bf16 = bf16((A@B^T + bias) * scale).
// ---------------------------------------------------------------------------
__global__ __launch_bounds__(256) void qkv_kernel(
    const ushort_t* __restrict__ XB, const ushort_t* __restrict__ WB,
    const float* __restrict__ bq, const float* __restrict__ bk,
    const float* __restrict__ bv, ushort_t* __restrict__ QB,
    ushort_t* __restrict__ KB, ushort_t* __restrict__ VB) {
  __shared__ __align__(16) ushort_t AS[128][32];
  __shared__ __align__(16) ushort_t BS[128][32];

  const int z = blockIdx.z;
  const ushort_t* Bmat = WB + (size_t)z * WMAT;
  const float* bias = (z == 0) ? bq : (z == 1) ? bk : bv;
  ushort_t* outp = (z == 0) ? QB : (z == 1) ? KB : VB;
  const float scale = (z == 0) ? QSCALE : 1.0f;

  const int t = threadIdx.x;
  const int lane = t & 63;
  const int w = t >> 6;
  const int tn = t & 15;
  const int g = (t >> 4) & 3;
  const int wr = w >> 1, wc = w & 1;
  const int m0 = blockIdx.x * 128;
  const int n0 = blockIdx.y * 128;

  f32x4 acc[4][4];
#pragma unroll
  for (int mi = 0; mi < 4; ++mi)
#pragma unroll
    for (int nj = 0; nj < 4; ++nj) acc[mi][nj] = (f32x4){0.f, 0.f, 0.f, 0.f};

  const int crow = lane >> 2;
  const int ccol = (lane & 3) * 8;

  for (int k0 = 0; k0 < EDIM; k0 += 32) {
    __syncthreads();
#pragma unroll
    for (int i = 0; i < 2; ++i) {
      const int ch = w + 4 * i;
      const int row = ch * 16 + crow;
      GLOAD_LDS16(XB + (size_t)(m0 + row) * EDIM + k0 + ccol, &AS[ch * 16][0]);
      GLOAD_LDS16(Bmat + (size_t)(n0 + row) * EDIM + k0 + ccol, &BS[ch * 16][0]);
    }
    __syncthreads();

    bf16x8 ah[4], bh[4];
#pragma unroll
    for (int mi = 0; mi < 4; ++mi)
      ah[mi] = __builtin_bit_cast(
          bf16x8, *(const u16x8*)&AS[wr * 64 + mi * 16 + tn][8 * g]);
#pragma unroll
    for (int nj = 0; nj < 4; ++nj)
      bh[nj] = __builtin_bit_cast(
          bf16x8, *(const u16x8*)&BS[wc * 64 + nj * 16 + tn][8 * g]);
#pragma unroll
    for (int mi = 0; mi < 4; ++mi)
#pragma unroll
      for (int nj = 0; nj < 4; ++nj)
        acc[mi][nj] = MFMA16(ah[mi], bh[nj], acc[mi][nj]);
  }

#pragma unroll
  for (int mi = 0; mi < 4; ++mi) {
    const int rb = m0 + wr * 64 + mi * 16 + 4 * g;
#pragma unroll
    for (int nj = 0; nj < 4; ++nj) {
      const int col = n0 + wc * 64 + nj * 16 + tn;
      const float bb = bias[col];
#pragma unroll
      for (int r = 0; r < 4; ++r)
        outp[(size_t)(rb + r) * EDIM + col] =
            bfbits((acc[mi][nj][r] + bb) * scale);
    }
  }
}

// ---------------------------------------------------------------------------
// 3-term split MFMA GEMM (for proj): fp32-accurate, fp32 out + bias.
// ---------------------------------------------------------------------------
__global__ __launch_bounds__(256) void proj_kernel(
    const ushort_t* __restrict__ Ah, const ushort_t* __restrict__ Al,
    const ushort_t* __restrict__ Bh, const ushort_t* __restrict__ Bl,
    const float* __restrict__ bias, float* __restrict__ outf) {
  __shared__ __align__(16) ushort_t AhS[128][32];
  __shared__ __align__(16) ushort_t AlS[128][32];
  __shared__ __align__(16) ushort_t BhS[128][32];
  __shared__ __align__(16) ushort_t BlS[128][32];

  const int t = threadIdx.x;
  const int lane = t & 63;
  const int w = t >> 6;
  const int tn = t & 15;
  const int g = (t >> 4) & 3;
  const int wr = w >> 1, wc = w & 1;
  const int m0 = blockIdx.x * 128;
  const int n0 = blockIdx.y * 128;

  f32x4 acc[4][4];
#pragma unroll
  for (int mi = 0; mi < 4; ++mi)
#pragma unroll
    for (int nj = 0; nj < 4; ++nj) acc[mi][nj] = (f32x4){0.f, 0.f, 0.f, 0.f};

  const int crow = lane >> 2;
  const int ccol = (lane & 3) * 8;

  for (int k0 = 0; k0 < EDIM; k0 += 32) {
    __syncthreads();
#pragma unroll
    for (int i = 0; i < 2; ++i) {
      const int ch = w + 4 * i;
      const int row = ch * 16 + crow;
      const size_t ga = (size_t)(m0 + row) * EDIM + k0 + ccol;
      const size_t gb = (size_t)(n0 + row) * EDIM + k0 + ccol;
      GLOAD_LDS16(Ah + ga, &AhS[ch * 16][0]);
      GLOAD_LDS16(Al + ga, &AlS[ch * 16][0]);
      GLOAD_LDS16(Bh + gb, &BhS[ch * 16][0]);
      GLOAD_LDS16(Bl + gb, &BlS[ch * 16][0]);
    }
    __syncthreads();

    bf16x8 ah[4], al[4], bh[4], bl[4];
#pragma unroll
    for (int mi = 0; mi < 4; ++mi) {
      ah[mi] = __builtin_bit_cast(
          bf16x8, *(const u16x8*)&AhS[wr * 64 + mi * 16 + tn][8 * g]);
      al[mi] = __builtin_bit_cast(
          bf16x8, *(const u16x8*)&AlS[wr * 64 + mi * 16 + tn][8 * g]);
    }
#pragma unroll
    for (int nj = 0; nj < 4; ++nj) {
      bh[nj] = __builtin_bit_cast(
          bf16x8, *(const u16x8*)&BhS[wc * 64 + nj * 16 + tn][8 * g]);
      bl[nj] = __builtin_bit_cast(
          bf16x8, *(const u16x8*)&BlS[wc * 64 + nj * 16 + tn][8 * g]);
    }
#pragma unroll
    for (int mi = 0; mi < 4; ++mi)
#pragma unroll
      for (int nj = 0; nj < 4; ++nj)
        acc[mi][nj] = MFMA16(ah[mi], bh[nj], acc[mi][nj]);
#pragma unroll
    for (int mi = 0; mi < 4; ++mi)
#pragma unroll
      for (int nj = 0; nj < 4; ++nj)
        acc[mi][nj] = MFMA16(al[mi], bh[nj], acc[mi][nj]);
#pragma unroll
    for (int mi = 0; mi < 4; ++mi)
#pragma unroll
      for (int nj = 0; nj < 4; ++nj)
        acc[mi][nj] = MFMA16(ah[mi], bl[nj], acc[mi][nj]);
  }

#pragma unroll
  for (int mi = 0; mi < 4; ++mi) {
    const int rb = m0 + wr * 64 + mi * 16 + 4 * g;
#pragma unroll
    for (int nj = 0; nj < 4; ++nj) {
      const int col = n0 + wc * 64 + nj * 16 + tn;
      const float bb = bias[col];
#pragma unroll
      for (int r = 0; r < 4; ++r)
        outf[(size_t)(rb + r) * EDIM + col] = acc[mi][nj][r] + bb;
    }
  }
}

// ---------------------------------------------------------------------------
// MFMA flash attention, 128 threads = 2 waves x 32 q-rows. K/V fragments are
// read once per wave and reused across both 16-row sub-blocks (halves the
// dominant LDS read traffic). Double-buffered K/V staging -> 1 barrier/tile;
// T14 register preload of next tile. No-max softmax in exp2 domain, rowsum
// via ones-MFMA. C written hi/lo split for the proj 3-term GEMM.
// ---------------------------------------------------------------------------
__global__ __launch_bounds__(128) void attn_kernel(
    const ushort_t* __restrict__ QB, const ushort_t* __restrict__ KBg,
    const ushort_t* __restrict__ Vg, ushort_t* __restrict__ Ch_g,
    ushort_t* __restrict__ Cl_g) {
  constexpr int DP = HDIM + 8;  // 72
  __shared__ __align__(16) ushort_t KS[2][64][DP];
  __shared__ __align__(16) ushort_t Vt[2][HDIM][DP];  // Vt[buf][d][key]
  __shared__ __align__(16) ushort_t Ps[2][32][DP];    // per-wave P

  const int t = threadIdx.x;
  const int tn = t & 15;
  const int g = (t >> 4) & 3;
  const int kg = g * 8;
  const int wid = t >> 6;  // 0..1
  const int h = blockIdx.y;
  const int q0 = blockIdx.x * 64;
  const int hoff = h * HDIM;

  // Q fragments: 2 row-blocks x 2 k-steps (pre-scaled bf16)
  bf16x8 qb[2][2];
#pragma unroll
  for (int rb = 0; rb < 2; ++rb) {
    const size_t qoff =
        (size_t)(q0 + 32 * wid + 16 * rb + tn) * EDIM + hoff;
#pragma unroll
    for (int st = 0; st < 2; ++st)
      qb[rb][st] = __builtin_bit_cast(
          bf16x8, *(const u16x8*)(QB + qoff + 32 * st + kg));
  }

  // staging roles (128 threads)
  const int kr = t >> 1;               // K row 0..63
  const int kc = (t & 1) * 32;         // K col 0/32
  const int vkey = (t & 31) * 2;       // V: two keys
  const int vd0 = ((t >> 5) & 3) * 16; // 16 dims

  u16x8 kreg[4], vreg[4];
  {
    const ushort_t* kp = KBg + (size_t)kr * EDIM + hoff + kc;
    kreg[0] = *(const u16x8*)kp;
    kreg[1] = *(const u16x8*)(kp + 8);
    kreg[2] = *(const u16x8*)(kp + 16);
    kreg[3] = *(const u16x8*)(kp + 24);
    const ushort_t* vp = Vg + (size_t)vkey * EDIM + hoff + vd0;
    vreg[0] = *(const u16x8*)vp;
    vreg[1] = *(const u16x8*)(vp + 8);
    vreg[2] = *(const u16x8*)(vp + EDIM);
    vreg[3] = *(const u16x8*)(vp + EDIM + 8);
  }

  const bf16x8 ones = ones8();
  f32x4 o[2][4], lsum[2];
#pragma unroll
  for (int rb = 0; rb < 2; ++rb) {
    lsum[rb] = (f32x4){0.f, 0.f, 0.f, 0.f};
#pragma unroll
    for (int j = 0; j < 4; ++j) o[rb][j] = (f32x4){0.f, 0.f, 0.f, 0.f};
  }

  for (int k0 = 0; k0 < SEQ; k0 += 64) {
    const int buf = (k0 >> 6) & 1;
    // staged regs -> LDS
    *(u16x8*)&KS[buf][kr][kc] = kreg[0];
    *(u16x8*)&KS[buf][kr][kc + 8] = kreg[1];
    *(u16x8*)&KS[buf][kr][kc + 16] = kreg[2];
    *(u16x8*)&KS[buf][kr][kc + 24] = kreg[3];
#pragma unroll
    for (int i = 0; i < 8; ++i) {
      *(uint_t*)&Vt[buf][vd0 + i][vkey] =
          (uint_t)vreg[0][i] | ((uint_t)vreg[2][i] << 16);
      *(uint_t*)&Vt[buf][vd0 + 8 + i][vkey] =
          (uint_t)vreg[1][i] | ((uint_t)vreg[3][i] << 16);
    }
    __syncthreads();  // single barrier: buf ready; buf^1 free for next writes

    if (k0 + 64 < SEQ) {  // T14 preload next tile into regs
      const ushort_t* kp = KBg + (size_t)(k0 + 64 + kr) * EDIM + hoff + kc;
      kreg[0] = *(const u16x8*)kp;
      kreg[1] = *(const u16x8*)(kp + 8);
      kreg[2] = *(const u16x8*)(kp + 16);
      kreg[3] = *(const u16x8*)(kp + 24);
      const ushort_t* vp =
          Vg + (size_t)(k0 + 64 + vkey) * EDIM + hoff + vd0;
      vreg[0] = *(const u16x8*)vp;
      vreg[1] = *(const u16x8*)(vp + 8);
      vreg[2] = *(const u16x8*)(vp + EDIM);
      vreg[3] = *(const u16x8*)(vp + EDIM + 8);
    }

    // S = Q K^T (log2-domain): K frags shared across both row-blocks
    f32x4 s[2][4];
#pragma unroll
    for (int rb = 0; rb < 2; ++rb)
#pragma unroll
      for (int j = 0; j < 4; ++j) s[rb][j] = (f32x4){0.f, 0.f, 0.f, 0.f};
#pragma unroll
    for (int j = 0; j < 4; ++j)
#pragma unroll
      for (int st = 0; st < 2; ++st) {
        const bf16x8 kb = __builtin_bit_cast(
            bf16x8, *(const u16x8*)&KS[buf][j * 16 + tn][32 * st + kg]);
        s[0][j] = MFMA16(qb[0][st], kb, s[0][j]);
        s[1][j] = MFMA16(qb[1][st], kb, s[1][j]);
      }

    // p = 2^s, store P (per-wave buffer, rows 16rb+4g+r)
#pragma unroll
    for (int rb = 0; rb < 2; ++rb)
#pragma unroll
      for (int r = 0; r < 4; ++r)
#pragma unroll
        for (int j = 0; j < 4; ++j)
          Ps[wid][16 * rb + 4 * g + r][16 * j + tn] =
              bfbits(exp2f(s[rb][j][r]));

    // O += P V ; lsum += P @ ones. V frags shared across row-blocks.
    bf16x8 pa[2][2];
#pragma unroll
    for (int rb = 0; rb < 2; ++rb)
#pragma unroll
      for (int st = 0; st < 2; ++st)
        pa[rb][st] = __builtin_bit_cast(
            bf16x8, *(const u16x8*)&Ps[wid][16 * rb + tn][32 * st + kg]);
#pragma unroll
    for (int j = 0; j < 4; ++j)
#pragma unroll
      for (int st = 0; st < 2; ++st) {
        const bf16x8 vb = __builtin_bit_cast(
            bf16x8, *(const u16x8*)&Vt[buf][j * 16 + tn][32 * st + kg]);
        o[0][j] = MFMA16(pa[0][st], vb, o[0][j]);
        o[1][j] = MFMA16(pa[1][st], vb, o[1][j]);
      }
#pragma unroll
    for (int rb = 0; rb < 2; ++rb) {
      lsum[rb] = MFMA16(pa[rb][0], ones, lsum[rb]);
      lsum[rb] = MFMA16(pa[rb][1], ones, lsum[rb]);
    }
  }

  // epilogue: normalize, split hi/lo, store C
#pragma unroll
  for (int rb = 0; rb < 2; ++rb)
#pragma unroll
    for (int r = 0; r < 4; ++r) {
      const float inv = 1.f / lsum[rb][r];
#pragma unroll
      for (int j = 0; j < 4; ++j) {
        const float val = o[rb][j][r] * inv;
        unsigned short hh, ll;
        split1(val, &hh, &ll);
        const size_t idx =
            (size_t)(q0 + 32 * wid + 16 * rb + 4 * g + r) * EDIM + hoff +
            16 * j + tn;
        Ch_g[idx] = hh;
        Cl_g[idx] = ll;
      }
    }
}

extern "C" void kernel_launch(void* const* d_in, const int* in_sizes, int n_in,
                              void* d_out, int out_size, void* d_ws,
                              size_t ws_size, hipStream_t stream) {
  const float* x  = (const float*)d_in[0];
  const float* Wq = (const float*)d_in[1];
  const float* bq = (const float*)d_in[2];
  const float* Wk = (const float*)d_in[3];
  const float* bk = (const float*)d_in[4];
  const float* Wv = (const float*)d_in[5];
  const float* bv = (const float*)d_in[6];
  const float* Wo = (const float*)d_in[7];
  const float* bo = (const float*)d_in[8];
  float* out = (float*)d_out;

  // ws layout, u16 elements (~43.7 MB)
  ushort_t* WB  = (ushort_t*)d_ws;              // 3*WMAT (Wq,Wk,Wv bf16)
  ushort_t* WOH = WB + (size_t)3 * WMAT;        // WMAT
  ushort_t* WOL = WOH + (size_t)WMAT;           // WMAT
  ushort_t* XB  = WOL + (size_t)WMAT;           // SE
  ushort_t* QB  = XB + (size_t)SE;              // SE
  ushort_t* KB  = QB + (size_t)SE;              // SE
  ushort_t* VB  = KB + (size_t)SE;              // SE
  ushort_t* CH  = VB + (size_t)SE;              // SE
  ushort_t* CL  = CH + (size_t)SE;              // SE

  dim3 gw(WMAT / 2048, 4);
  wprep_kernel<<<gw, 256, 0, stream>>>(Wq, Wk, Wv, Wo, WB, WOH, WOL);
  xprep_kernel<<<SE / 2048, 256, 0, stream>>>(x, XB);

  dim3 gq(SEQ / 128, EDIM / 128, 3);
  qkv_kernel<<<gq, 256, 0, stream>>>(XB, WB, bq, bk, bv, QB, KB, VB);

  dim3 ga(SEQ / 64, NHEAD);
  attn_kernel<<<ga, 128, 0, stream>>>(QB, KB, VB, CH, CL);

  dim3 go(SEQ / 128, EDIM / 128);
  proj_kernel<<<go, 256, 0, stream>>>(CH, CL, WOH, WOL, bo, out);
}